// Round 8
// baseline (81.924 us; speedup 1.0000x reference)
//
#include <hip/hip_runtime.h>

#define NN 32
#define MM 128
#define EE 256
#define DD 128
#define ELB 16   // e's per k_main block

typedef __attribute__((ext_vector_type(8))) short short8;
typedef __attribute__((ext_vector_type(4))) float f32x4;

union U16x8 { uint4 u; short8 s; };

static __device__ __forceinline__ unsigned short f2bf(float f) {
  union { float f; unsigned u; } v; v.f = f;
  unsigned r = v.u + 0x7FFFu + ((v.u >> 16) & 1u);   // RNE
  return (unsigned short)(r >> 16);
}

// ---------------- kernel 1: L = einsum('nd,jd->nj') per i, softmax -> P1 (bf16); P0 = softmax(bkk) ----
__global__ __launch_bounds__(128, 1)
void k_prep(const float* __restrict__ X, const float* __restrict__ Wkk,
            const float* __restrict__ bkk,
            unsigned short* __restrict__ P1g, unsigned short* __restrict__ P0g) {
  const int i  = blockIdx.x;
  const int ty = threadIdx.x >> 6;       // wave = row-frag (n 16-block)
  const int l  = threadIdx.x & 63;
  const int lr = l & 15, lg = l >> 4;

  short8 a[4];
  {
    const int n = ty * 16 + lr;
    const float* xp = X + (n * MM + i) * DD + lg * 8;
#pragma unroll
    for (int k = 0; k < 4; ++k) {
      float4 v0 = *(const float4*)(xp + k * 32);
      float4 v1 = *(const float4*)(xp + k * 32 + 4);
      short8 s;
      s[0]=(short)f2bf(v0.x); s[1]=(short)f2bf(v0.y); s[2]=(short)f2bf(v0.z); s[3]=(short)f2bf(v0.w);
      s[4]=(short)f2bf(v1.x); s[5]=(short)f2bf(v1.y); s[6]=(short)f2bf(v1.z); s[7]=(short)f2bf(v1.w);
      a[k] = s;
    }
  }
  f32x4 acc[8];
#pragma unroll
  for (int cf = 0; cf < 8; ++cf) acc[cf] = (f32x4){0.f, 0.f, 0.f, 0.f};

#pragma unroll
  for (int k = 0; k < 4; ++k) {
#pragma unroll
    for (int cf = 0; cf < 8; ++cf) {
      const int j = cf * 16 + lr;
      const float* wp = Wkk + (i * MM + j) * DD + k * 32 + lg * 8;
      float4 v0 = *(const float4*)(wp);
      float4 v1 = *(const float4*)(wp + 4);
      short8 b;
      b[0]=(short)f2bf(v0.x); b[1]=(short)f2bf(v0.y); b[2]=(short)f2bf(v0.z); b[3]=(short)f2bf(v0.w);
      b[4]=(short)f2bf(v1.x); b[5]=(short)f2bf(v1.y); b[6]=(short)f2bf(v1.z); b[7]=(short)f2bf(v1.w);
      acc[cf] = __builtin_amdgcn_mfma_f32_16x16x32_bf16(a[k], b, acc[cf], 0, 0, 0);
    }
  }

  float bk[8];
#pragma unroll
  for (int cf = 0; cf < 8; ++cf) bk[cf] = bkk[i * MM + cf * 16 + lr];

#pragma unroll
  for (int r = 0; r < 4; ++r) {
    float v[8], m = -1e30f;
#pragma unroll
    for (int cf = 0; cf < 8; ++cf) { v[cf] = acc[cf][r] + bk[cf]; m = fmaxf(m, v[cf]); }
#pragma unroll
    for (int s = 1; s < 16; s <<= 1) m = fmaxf(m, __shfl_xor(m, s, 64));
    float sum = 0.f;
#pragma unroll
    for (int cf = 0; cf < 8; ++cf) { v[cf] = __expf(v[cf] - m); sum += v[cf]; }
#pragma unroll
    for (int s = 1; s < 16; s <<= 1) sum += __shfl_xor(sum, s, 64);
    const float inv = 1.f / sum;
    const int n = ty * 16 + lg * 4 + r;
    unsigned short* dst = P1g + (n * MM + i) * MM;
#pragma unroll
    for (int cf = 0; cf < 8; ++cf) dst[cf * 16 + lr] = f2bf(v[cf] * inv);
  }

  if (ty == 0) {  // P0 row i
    float v0 = bkk[i * MM + l], v1 = bkk[i * MM + 64 + l];
    float m = fmaxf(v0, v1);
#pragma unroll
    for (int s = 1; s < 64; s <<= 1) m = fmaxf(m, __shfl_xor(m, s, 64));
    v0 = __expf(v0 - m); v1 = __expf(v1 - m);
    float sum = v0 + v1;
#pragma unroll
    for (int s = 1; s < 64; s <<= 1) sum += __shfl_xor(sum, s, 64);
    const float inv = 1.f / sum;
    P0g[i * MM + l]      = f2bf(v0 * inv);
    P0g[i * MM + 64 + l] = f2bf(v1 * inv);
  }
}

// ---------------- kernel 1b: per-n aux: XT[n][d][j] = bf16(X[n][j][d])  +  incidence bitmaps ------
__global__ __launch_bounds__(256, 1)
void k_aux(const float* __restrict__ X, const float* __restrict__ inc,
           unsigned short* __restrict__ XTg, unsigned* __restrict__ bmap) {
  __shared__ float xs[128][129];
  const int n = blockIdx.x, t = threadIdx.x;
#pragma unroll
  for (int it = 0; it < 16; ++it) {
    int idx = it * 256 + t;           // 0..4095 float4 tiles
    int j = idx >> 5, dq = idx & 31;
    float4 v = *(const float4*)(X + (n * MM + j) * DD + dq * 4);
    xs[j][dq * 4 + 0] = v.x; xs[j][dq * 4 + 1] = v.y;
    xs[j][dq * 4 + 2] = v.z; xs[j][dq * 4 + 3] = v.w;
  }
  __syncthreads();
  {
    const int d = t >> 1, jh = t & 1;
    unsigned* dst = (unsigned*)XTg + (n * DD + d) * (MM / 2) + jh * 32;
#pragma unroll
    for (int jj = 0; jj < 32; ++jj) {
      int j = jh * 64 + jj * 2;
      unsigned u0 = f2bf(xs[j][d]), u1 = f2bf(xs[j + 1][d]);
      dst[jj] = u0 | (u1 << 16);
    }
  }
  // incidence bitmaps, coalesced over e = t
  {
    const int e = t;
    unsigned bm[4] = {0u, 0u, 0u, 0u};
#pragma unroll
    for (int q = 0; q < 4; ++q)
#pragma unroll 4
      for (int j = 0; j < 32; ++j)
        if (inc[(n * MM + q * 32 + j) * EE + e] != 0.f) bm[q] |= 1u << j;
    uint4 v; v.x = bm[0]; v.y = bm[1]; v.z = bm[2]; v.w = bm[3];
    *(uint4*)(bmap + (n * EE + e) * 4) = v;
  }
}

// ---------------- kernel 2: main. 1024 blocks = 32n x 16eg x 2rh. Computes T^T = XT * P^T. ------
// XT[n] staged in LDS (XOR-swizzled); P rows + w1 frags pinned in registers; MFMA d-reduce epilogue.
// 2 e's per inner iteration share each X-fragment ds_read (LDS-BW was the R7 bottleneck).
__global__ __launch_bounds__(256, 2)
void k_main(const unsigned short* __restrict__ P0g, const unsigned short* __restrict__ P1g,
            const unsigned short* __restrict__ XTg, const unsigned* __restrict__ bmap,
            const float* __restrict__ w1, const float* __restrict__ b1p,
            float* __restrict__ out) {
  __shared__ alignas(128) unsigned short XTlds[128][128];   // 32 KB, XOR-swizzled
  __shared__ unsigned bitm[ELB][4];
  __shared__ alignas(16) unsigned short mrow[ELB][128];     // 4 KB

  const int bid = blockIdx.x;
  const int n = bid & 31, eg = (bid >> 5) & 15, rh = bid >> 9;
  const int t = threadIdx.x, w = t >> 6, l = t & 63, lr = l & 15, lg = l >> 4;
  const int i_lane = rh * 64 + w * 16 + lr;   // this lane's P row / output-col index

  { // stage XT[n] with xor-swizzle ^((row&7)<<4); row = byte>>8 = idx>>4   (verified pair, R2)
    char* d2 = (char*)&XTlds[0][0];
    const uint4* s2 = (const uint4*)(XTg + n * DD * MM);
#pragma unroll
    for (int it = 0; it < 8; ++it) {
      int idx = it * 256 + t;                       // 0..2047 16B chunks
      int off = (idx * 16) ^ (((idx >> 4) & 7) << 4);
      *(uint4*)(d2 + off) = s2[idx];
    }
  }
  if (t < ELB)
    *(uint4*)&bitm[t][0] = *(const uint4*)(bmap + (n * EE + eg * ELB + t) * 4);

  // P fragments (B-operands): row i_lane, k-slices  -- loaded ONCE, pinned below
  uint4 p0[4], p1[4];
  {
    const unsigned short* pb0 = P0g + i_lane * MM;
    const unsigned short* pb1 = P1g + n * MM * MM + i_lane * MM;
#pragma unroll
    for (int k = 0; k < 4; ++k) {
      p0[k] = *(const uint4*)(pb0 + k * 32 + lg * 8);
      p1[k] = *(const uint4*)(pb1 + k * 32 + lg * 8);
    }
  }
  // w1 B-fragments, packed per cf-pair to match the custom K=32 epilogue contraction
  U16x8 w1u[4];
#pragma unroll
  for (int p = 0; p < 4; ++p) {
    float4 a = *(const float4*)(w1 + (2 * p) * 16 + lg * 4);
    float4 b = *(const float4*)(w1 + (2 * p + 1) * 16 + lg * 4);
    short8 s;
    s[0]=(short)f2bf(a.x); s[1]=(short)f2bf(a.y); s[2]=(short)f2bf(a.z); s[3]=(short)f2bf(a.w);
    s[4]=(short)f2bf(b.x); s[5]=(short)f2bf(b.y); s[6]=(short)f2bf(b.z); s[7]=(short)f2bf(b.w);
    w1u[p].s = s;
  }
  // PIN loop-invariants in registers: read-write asm makes sinking/remat illegal.
#pragma unroll
  for (int k = 0; k < 4; ++k) {
    asm volatile("" : "+v"(p0[k].x), "+v"(p0[k].y), "+v"(p0[k].z), "+v"(p0[k].w));
    asm volatile("" : "+v"(p1[k].x), "+v"(p1[k].y), "+v"(p1[k].z), "+v"(p1[k].w));
    asm volatile("" : "+v"(w1u[k].u.x), "+v"(w1u[k].u.y), "+v"(w1u[k].u.z), "+v"(w1u[k].u.w));
  }
  const float b1v = b1p[0];
  const int selsh = (w & 1) * 16 + lr;
  const int selwd = rh * 2 + (w >> 1);
  __syncthreads();

  if (t < ELB * 8) {  // expand bitmap -> u16 AND-masks over contracted dim j
    int el = t >> 3, j0 = (t & 7) * 16;
    unsigned wd = bitm[el][j0 >> 5];
    int sh = j0 & 31;
    unsigned short* mp = &mrow[el][j0];
#pragma unroll
    for (int b = 0; b < 16; ++b) mp[b] = ((wd >> (sh + b)) & 1u) ? 0xFFFFu : 0u;
  }
  __syncthreads();

  // A-read: off = (row*256 + k*64 + lg*16) ^ ((row&7)<<4), row = cf*16+lr.
  // row*256 lives in bits>=8; XOR field is bits 4..7 -> keep the XOR inside (k*64+lg*16).
  const char* xbase = (const char*)&XTlds[0][0] + lr * 256;
  const int xmask = (lr & 7) << 4;
  float* outp = out + (n * EE + eg * ELB) * MM + rh * 64 + w * 16 + lg * 4;

#pragma unroll 1
  for (int ep = 0; ep < ELB / 2; ++ep) {
    const int el0 = ep * 2, el1 = ep * 2 + 1;
    const bool selA = ((bitm[el0][selwd] >> selsh) & 1u) != 0u;
    const bool selB = ((bitm[el1][selwd] >> selsh) & 1u) != 0u;
    f32x4 accA[8], accB[8];
#pragma unroll
    for (int cf = 0; cf < 8; ++cf) {
      accA[cf] = (f32x4){0.f, 0.f, 0.f, 0.f};
      accB[cf] = (f32x4){0.f, 0.f, 0.f, 0.f};
    }

#pragma unroll
    for (int k = 0; k < 4; ++k) {
      uint4 mmA = *(const uint4*)((const char*)&mrow[el0][0] + k * 64 + lg * 16);
      uint4 mmB = *(const uint4*)((const char*)&mrow[el1][0] + k * 64 + lg * 16);
      U16x8 pvA, pvB;
      pvA.u.x = (selA ? p1[k].x : p0[k].x) & mmA.x;
      pvA.u.y = (selA ? p1[k].y : p0[k].y) & mmA.y;
      pvA.u.z = (selA ? p1[k].z : p0[k].z) & mmA.z;
      pvA.u.w = (selA ? p1[k].w : p0[k].w) & mmA.w;
      pvB.u.x = (selB ? p1[k].x : p0[k].x) & mmB.x;
      pvB.u.y = (selB ? p1[k].y : p0[k].y) & mmB.y;
      pvB.u.z = (selB ? p1[k].z : p0[k].z) & mmB.z;
      pvB.u.w = (selB ? p1[k].w : p0[k].w) & mmB.w;
      const int xko = (k * 64 + lg * 16) ^ xmask;
#pragma unroll
      for (int cf = 0; cf < 8; ++cf) {
        U16x8 xv; xv.u = *(const uint4*)(xbase + cf * 4096 + xko);
        accA[cf] = __builtin_amdgcn_mfma_f32_16x16x32_bf16(xv.s, pvA.s, accA[cf], 0, 0, 0);
        accB[cf] = __builtin_amdgcn_mfma_f32_16x16x32_bf16(xv.s, pvB.s, accB[cf], 0, 0, 0);
      }
    }

    // epilogue A: relu -> bf16, reduce over d with 2 independent MFMA chains
    {
      f32x4 e0 = (f32x4){b1v, b1v, b1v, b1v};
      f32x4 e1 = (f32x4){0.f, 0.f, 0.f, 0.f};
#pragma unroll
      for (int p = 0; p < 4; ++p) {
        float a0 = fmaxf(accA[2*p][0], 0.f), a1 = fmaxf(accA[2*p][1], 0.f);
        float a2 = fmaxf(accA[2*p][2], 0.f), a3 = fmaxf(accA[2*p][3], 0.f);
        float c0 = fmaxf(accA[2*p+1][0], 0.f), c1 = fmaxf(accA[2*p+1][1], 0.f);
        float c2 = fmaxf(accA[2*p+1][2], 0.f), c3 = fmaxf(accA[2*p+1][3], 0.f);
        unsigned u0, u1, u2, u3;
        asm("v_cvt_pk_bf16_f32 %0, %1, %2" : "=v"(u0) : "v"(a0), "v"(a1));
        asm("v_cvt_pk_bf16_f32 %0, %1, %2" : "=v"(u1) : "v"(a2), "v"(a3));
        asm("v_cvt_pk_bf16_f32 %0, %1, %2" : "=v"(u2) : "v"(c0), "v"(c1));
        asm("v_cvt_pk_bf16_f32 %0, %1, %2" : "=v"(u3) : "v"(c2), "v"(c3));
        U16x8 uu; uu.u.x = u0; uu.u.y = u1; uu.u.z = u2; uu.u.w = u3;
        if (p & 1)
          e1 = __builtin_amdgcn_mfma_f32_16x16x32_bf16(uu.s, w1u[p].s, e1, 0, 0, 0);
        else
          e0 = __builtin_amdgcn_mfma_f32_16x16x32_bf16(uu.s, w1u[p].s, e0, 0, 0, 0);
      }
      e0[0] += e1[0]; e0[1] += e1[1]; e0[2] += e1[2]; e0[3] += e1[3];
      if (lr == 0) *(float4*)(outp + el0 * MM) = *(float4*)&e0;
    }
    // epilogue B
    {
      f32x4 e0 = (f32x4){b1v, b1v, b1v, b1v};
      f32x4 e1 = (f32x4){0.f, 0.f, 0.f, 0.f};
#pragma unroll
      for (int p = 0; p < 4; ++p) {
        float a0 = fmaxf(accB[2*p][0], 0.f), a1 = fmaxf(accB[2*p][1], 0.f);
        float a2 = fmaxf(accB[2*p][2], 0.f), a3 = fmaxf(accB[2*p][3], 0.f);
        float c0 = fmaxf(accB[2*p+1][0], 0.f), c1 = fmaxf(accB[2*p+1][1], 0.f);
        float c2 = fmaxf(accB[2*p+1][2], 0.f), c3 = fmaxf(accB[2*p+1][3], 0.f);
        unsigned u0, u1, u2, u3;
        asm("v_cvt_pk_bf16_f32 %0, %1, %2" : "=v"(u0) : "v"(a0), "v"(a1));
        asm("v_cvt_pk_bf16_f32 %0, %1, %2" : "=v"(u1) : "v"(a2), "v"(a3));
        asm("v_cvt_pk_bf16_f32 %0, %1, %2" : "=v"(u2) : "v"(c0), "v"(c1));
        asm("v_cvt_pk_bf16_f32 %0, %1, %2" : "=v"(u3) : "v"(c2), "v"(c3));
        U16x8 uu; uu.u.x = u0; uu.u.y = u1; uu.u.z = u2; uu.u.w = u3;
        if (p & 1)
          e1 = __builtin_amdgcn_mfma_f32_16x16x32_bf16(uu.s, w1u[p].s, e1, 0, 0, 0);
        else
          e0 = __builtin_amdgcn_mfma_f32_16x16x32_bf16(uu.s, w1u[p].s, e0, 0, 0, 0);
      }
      e0[0] += e1[0]; e0[1] += e1[1]; e0[2] += e1[2]; e0[3] += e1[3];
      if (lr == 0) *(float4*)(outp + el1 * MM) = *(float4*)&e0;
    }
  }
}

extern "C" void kernel_launch(void* const* d_in, const int* in_sizes, int n_in,
                              void* d_out, int out_size, void* d_ws, size_t ws_size,
                              hipStream_t stream) {
  const float* X   = (const float*)d_in[0];
  const float* inc = (const float*)d_in[1];
  const float* Wkk = (const float*)d_in[2];
  const float* bkk = (const float*)d_in[3];
  const float* w1  = (const float*)d_in[4];
  const float* b1  = (const float*)d_in[5];
  float* out = (float*)d_out;

  unsigned short* P1g = (unsigned short*)d_ws;          // 32*128*128 u16 = 1 MB
  unsigned short* XTg = P1g + NN * MM * DD;             // 1 MB
  unsigned short* P0g = XTg + NN * MM * DD;             // 32 KB
  unsigned* bmap = (unsigned*)(P0g + MM * MM);          // 32*256*4 u32 = 128 KB

  hipLaunchKernelGGL(k_prep, dim3(128), dim3(128), 0, stream, X, Wkk, bkk, P1g, P0g);
  hipLaunchKernelGGL(k_aux,  dim3(32),  dim3(256), 0, stream, X, inc, XTg, bmap);
  hipLaunchKernelGGL(k_main, dim3(1024), dim3(256), 0, stream, P0g, P1g, XTg, bmap, w1, b1, out);
}

// Round 9
// 58.101 us; speedup vs baseline: 1.4100x; 1.4100x over previous
//
#include <hip/hip_runtime.h>

#define NN 32
#define MM 128
#define EE 256
#define DD 128
#define ELB 16   // e's per k_main block

typedef __attribute__((ext_vector_type(8))) short short8;
typedef __attribute__((ext_vector_type(4))) float f32x4;

union U16x8 { uint4 u; short8 s; };

static __device__ __forceinline__ unsigned short f2bf(float f) {
  union { float f; unsigned u; } v; v.f = f;
  unsigned r = v.u + 0x7FFFu + ((v.u >> 16) & 1u);   // RNE
  return (unsigned short)(r >> 16);
}

// ---------------- kernel 1: L = einsum('nd,jd->nj') per i, softmax -> P1 (bf16); P0 = softmax(bkk) ----
__global__ __launch_bounds__(128, 1)
void k_prep(const float* __restrict__ X, const float* __restrict__ Wkk,
            const float* __restrict__ bkk,
            unsigned short* __restrict__ P1g, unsigned short* __restrict__ P0g) {
  const int i  = blockIdx.x;
  const int ty = threadIdx.x >> 6;       // wave = row-frag (n 16-block)
  const int l  = threadIdx.x & 63;
  const int lr = l & 15, lg = l >> 4;

  short8 a[4];
  {
    const int n = ty * 16 + lr;
    const float* xp = X + (n * MM + i) * DD + lg * 8;
#pragma unroll
    for (int k = 0; k < 4; ++k) {
      float4 v0 = *(const float4*)(xp + k * 32);
      float4 v1 = *(const float4*)(xp + k * 32 + 4);
      short8 s;
      s[0]=(short)f2bf(v0.x); s[1]=(short)f2bf(v0.y); s[2]=(short)f2bf(v0.z); s[3]=(short)f2bf(v0.w);
      s[4]=(short)f2bf(v1.x); s[5]=(short)f2bf(v1.y); s[6]=(short)f2bf(v1.z); s[7]=(short)f2bf(v1.w);
      a[k] = s;
    }
  }
  f32x4 acc[8];
#pragma unroll
  for (int cf = 0; cf < 8; ++cf) acc[cf] = (f32x4){0.f, 0.f, 0.f, 0.f};

#pragma unroll
  for (int k = 0; k < 4; ++k) {
#pragma unroll
    for (int cf = 0; cf < 8; ++cf) {
      const int j = cf * 16 + lr;
      const float* wp = Wkk + (i * MM + j) * DD + k * 32 + lg * 8;
      float4 v0 = *(const float4*)(wp);
      float4 v1 = *(const float4*)(wp + 4);
      short8 b;
      b[0]=(short)f2bf(v0.x); b[1]=(short)f2bf(v0.y); b[2]=(short)f2bf(v0.z); b[3]=(short)f2bf(v0.w);
      b[4]=(short)f2bf(v1.x); b[5]=(short)f2bf(v1.y); b[6]=(short)f2bf(v1.z); b[7]=(short)f2bf(v1.w);
      acc[cf] = __builtin_amdgcn_mfma_f32_16x16x32_bf16(a[k], b, acc[cf], 0, 0, 0);
    }
  }

  float bk[8];
#pragma unroll
  for (int cf = 0; cf < 8; ++cf) bk[cf] = bkk[i * MM + cf * 16 + lr];

#pragma unroll
  for (int r = 0; r < 4; ++r) {
    float v[8], m = -1e30f;
#pragma unroll
    for (int cf = 0; cf < 8; ++cf) { v[cf] = acc[cf][r] + bk[cf]; m = fmaxf(m, v[cf]); }
#pragma unroll
    for (int s = 1; s < 16; s <<= 1) m = fmaxf(m, __shfl_xor(m, s, 64));
    float sum = 0.f;
#pragma unroll
    for (int cf = 0; cf < 8; ++cf) { v[cf] = __expf(v[cf] - m); sum += v[cf]; }
#pragma unroll
    for (int s = 1; s < 16; s <<= 1) sum += __shfl_xor(sum, s, 64);
    const float inv = 1.f / sum;
    const int n = ty * 16 + lg * 4 + r;
    unsigned short* dst = P1g + (n * MM + i) * MM;
#pragma unroll
    for (int cf = 0; cf < 8; ++cf) dst[cf * 16 + lr] = f2bf(v[cf] * inv);
  }

  if (ty == 0) {  // P0 row i
    float v0 = bkk[i * MM + l], v1 = bkk[i * MM + 64 + l];
    float m = fmaxf(v0, v1);
#pragma unroll
    for (int s = 1; s < 64; s <<= 1) m = fmaxf(m, __shfl_xor(m, s, 64));
    v0 = __expf(v0 - m); v1 = __expf(v1 - m);
    float sum = v0 + v1;
#pragma unroll
    for (int s = 1; s < 64; s <<= 1) sum += __shfl_xor(sum, s, 64);
    const float inv = 1.f / sum;
    P0g[i * MM + l]      = f2bf(v0 * inv);
    P0g[i * MM + 64 + l] = f2bf(v1 * inv);
  }
}

// ---------------- kernel 1b: per-n aux: XT[n][d][j] = bf16(X[n][j][d])  +  incidence bitmaps ------
__global__ __launch_bounds__(256, 1)
void k_aux(const float* __restrict__ X, const float* __restrict__ inc,
           unsigned short* __restrict__ XTg, unsigned* __restrict__ bmap) {
  __shared__ float xs[128][129];
  const int n = blockIdx.x, t = threadIdx.x;
#pragma unroll
  for (int it = 0; it < 16; ++it) {
    int idx = it * 256 + t;           // 0..4095 float4 tiles
    int j = idx >> 5, dq = idx & 31;
    float4 v = *(const float4*)(X + (n * MM + j) * DD + dq * 4);
    xs[j][dq * 4 + 0] = v.x; xs[j][dq * 4 + 1] = v.y;
    xs[j][dq * 4 + 2] = v.z; xs[j][dq * 4 + 3] = v.w;
  }
  __syncthreads();
  {
    const int d = t >> 1, jh = t & 1;
    unsigned* dst = (unsigned*)XTg + (n * DD + d) * (MM / 2) + jh * 32;
#pragma unroll
    for (int jj = 0; jj < 32; ++jj) {
      int j = jh * 64 + jj * 2;
      unsigned u0 = f2bf(xs[j][d]), u1 = f2bf(xs[j + 1][d]);
      dst[jj] = u0 | (u1 << 16);
    }
  }
  // incidence bitmaps, coalesced over e = t
  {
    const int e = t;
    unsigned bm[4] = {0u, 0u, 0u, 0u};
#pragma unroll
    for (int q = 0; q < 4; ++q)
#pragma unroll 4
      for (int j = 0; j < 32; ++j)
        if (inc[(n * MM + q * 32 + j) * EE + e] != 0.f) bm[q] |= 1u << j;
    uint4 v; v.x = bm[0]; v.y = bm[1]; v.z = bm[2]; v.w = bm[3];
    *(uint4*)(bmap + (n * EE + e) * 4) = v;
  }
}

// ---------------- kernel 2: main. 1024 blocks = 32n x 16eg x 2rh. Computes T^T = XT * P^T. ------
// XT[n] in LDS (XOR-swizzled); P rows + w1 frags pinned in regs; 2 e's share each X ds_read;
// cf-pair-wise accumulation keeps only 16 acc VGPRs live (R8 spilled with 64).
__global__ __launch_bounds__(256, 2)
void k_main(const unsigned short* __restrict__ P0g, const unsigned short* __restrict__ P1g,
            const unsigned short* __restrict__ XTg, const unsigned* __restrict__ bmap,
            const float* __restrict__ w1, const float* __restrict__ b1p,
            float* __restrict__ out) {
  __shared__ alignas(128) unsigned short XTlds[128][128];   // 32 KB, XOR-swizzled
  __shared__ unsigned bitm[ELB][4];
  __shared__ alignas(16) unsigned short mrow[ELB][128];     // 4 KB

  const int bid = blockIdx.x;
  const int n = bid & 31, eg = (bid >> 5) & 15, rh = bid >> 9;
  const int t = threadIdx.x, w = t >> 6, l = t & 63, lr = l & 15, lg = l >> 4;
  const int i_lane = rh * 64 + w * 16 + lr;   // this lane's P row / output-col index

  { // stage XT[n] with xor-swizzle ^((row&7)<<4); row = byte>>8 = idx>>4   (verified pair, R2)
    char* d2 = (char*)&XTlds[0][0];
    const uint4* s2 = (const uint4*)(XTg + n * DD * MM);
#pragma unroll
    for (int it = 0; it < 8; ++it) {
      int idx = it * 256 + t;                       // 0..2047 16B chunks
      int off = (idx * 16) ^ (((idx >> 4) & 7) << 4);
      *(uint4*)(d2 + off) = s2[idx];
    }
  }
  if (t < ELB)
    *(uint4*)&bitm[t][0] = *(const uint4*)(bmap + (n * EE + eg * ELB + t) * 4);

  // P fragments (B-operands): row i_lane, k-slices  -- loaded ONCE, pinned below
  uint4 p0[4], p1[4];
  {
    const unsigned short* pb0 = P0g + i_lane * MM;
    const unsigned short* pb1 = P1g + n * MM * MM + i_lane * MM;
#pragma unroll
    for (int k = 0; k < 4; ++k) {
      p0[k] = *(const uint4*)(pb0 + k * 32 + lg * 8);
      p1[k] = *(const uint4*)(pb1 + k * 32 + lg * 8);
    }
  }
  // w1 B-fragments, packed per cf-pair to match the custom K=32 epilogue contraction
  U16x8 w1u[4];
#pragma unroll
  for (int p = 0; p < 4; ++p) {
    float4 a = *(const float4*)(w1 + (2 * p) * 16 + lg * 4);
    float4 b = *(const float4*)(w1 + (2 * p + 1) * 16 + lg * 4);
    short8 s;
    s[0]=(short)f2bf(a.x); s[1]=(short)f2bf(a.y); s[2]=(short)f2bf(a.z); s[3]=(short)f2bf(a.w);
    s[4]=(short)f2bf(b.x); s[5]=(short)f2bf(b.y); s[6]=(short)f2bf(b.z); s[7]=(short)f2bf(b.w);
    w1u[p].s = s;
  }
  // PIN loop-invariants in registers: read-write asm makes sinking/remat illegal.
#pragma unroll
  for (int k = 0; k < 4; ++k) {
    asm volatile("" : "+v"(p0[k].x), "+v"(p0[k].y), "+v"(p0[k].z), "+v"(p0[k].w));
    asm volatile("" : "+v"(p1[k].x), "+v"(p1[k].y), "+v"(p1[k].z), "+v"(p1[k].w));
    asm volatile("" : "+v"(w1u[k].u.x), "+v"(w1u[k].u.y), "+v"(w1u[k].u.z), "+v"(w1u[k].u.w));
  }
  const float b1v = b1p[0];
  const int selsh = (w & 1) * 16 + lr;
  const int selwd = rh * 2 + (w >> 1);
  __syncthreads();

  if (t < ELB * 8) {  // expand bitmap -> u16 AND-masks over contracted dim j
    int el = t >> 3, j0 = (t & 7) * 16;
    unsigned wd = bitm[el][j0 >> 5];
    int sh = j0 & 31;
    unsigned short* mp = &mrow[el][j0];
#pragma unroll
    for (int b = 0; b < 16; ++b) mp[b] = ((wd >> (sh + b)) & 1u) ? 0xFFFFu : 0u;
  }
  __syncthreads();

  // A-read: off = (row*256 + k*64 + lg*16) ^ ((row&7)<<4), row = cf*16+lr.
  // row*256 lives in bits>=8; XOR field is bits 4..7 -> keep the XOR inside (k*64+lg*16).
  const char* xbase = (const char*)&XTlds[0][0] + lr * 256;
  const int xmask = (lr & 7) << 4;
  float* outp = out + (n * EE + eg * ELB) * MM + rh * 64 + w * 16 + lg * 4;

#pragma unroll 1
  for (int ep = 0; ep < ELB / 2; ++ep) {
    const int el0 = ep * 2, el1 = ep * 2 + 1;
    const bool selA = ((bitm[el0][selwd] >> selsh) & 1u) != 0u;
    const bool selB = ((bitm[el1][selwd] >> selsh) & 1u) != 0u;

    // select+mask P once per e (k-slices), reused across all cf-pairs
    U16x8 pvA[4], pvB[4];
#pragma unroll
    for (int k = 0; k < 4; ++k) {
      uint4 mmA = *(const uint4*)((const char*)&mrow[el0][0] + k * 64 + lg * 16);
      uint4 mmB = *(const uint4*)((const char*)&mrow[el1][0] + k * 64 + lg * 16);
      pvA[k].u.x = (selA ? p1[k].x : p0[k].x) & mmA.x;
      pvA[k].u.y = (selA ? p1[k].y : p0[k].y) & mmA.y;
      pvA[k].u.z = (selA ? p1[k].z : p0[k].z) & mmA.z;
      pvA[k].u.w = (selA ? p1[k].w : p0[k].w) & mmA.w;
      pvB[k].u.x = (selB ? p1[k].x : p0[k].x) & mmB.x;
      pvB[k].u.y = (selB ? p1[k].y : p0[k].y) & mmB.y;
      pvB[k].u.z = (selB ? p1[k].z : p0[k].z) & mmB.z;
      pvB[k].u.w = (selB ? p1[k].w : p0[k].w) & mmB.w;
    }

    f32x4 eA = (f32x4){b1v, b1v, b1v, b1v};
    f32x4 eB = (f32x4){b1v, b1v, b1v, b1v};

#pragma unroll
    for (int p = 0; p < 4; ++p) {
      f32x4 aA0 = (f32x4){0.f,0.f,0.f,0.f}, aA1 = (f32x4){0.f,0.f,0.f,0.f};
      f32x4 aB0 = (f32x4){0.f,0.f,0.f,0.f}, aB1 = (f32x4){0.f,0.f,0.f,0.f};
#pragma unroll
      for (int k = 0; k < 4; ++k) {
        const int xko = (k * 64 + lg * 16) ^ xmask;
        U16x8 xv0; xv0.u = *(const uint4*)(xbase + (2*p)   * 4096 + xko);
        U16x8 xv1; xv1.u = *(const uint4*)(xbase + (2*p+1) * 4096 + xko);
        aA0 = __builtin_amdgcn_mfma_f32_16x16x32_bf16(xv0.s, pvA[k].s, aA0, 0, 0, 0);
        aA1 = __builtin_amdgcn_mfma_f32_16x16x32_bf16(xv1.s, pvA[k].s, aA1, 0, 0, 0);
        aB0 = __builtin_amdgcn_mfma_f32_16x16x32_bf16(xv0.s, pvB[k].s, aB0, 0, 0, 0);
        aB1 = __builtin_amdgcn_mfma_f32_16x16x32_bf16(xv1.s, pvB[k].s, aB1, 0, 0, 0);
      }
      // fold this cf-pair into the per-e pooled chain
      {
        float a0 = fmaxf(aA0[0],0.f), a1 = fmaxf(aA0[1],0.f), a2 = fmaxf(aA0[2],0.f), a3 = fmaxf(aA0[3],0.f);
        float c0 = fmaxf(aA1[0],0.f), c1 = fmaxf(aA1[1],0.f), c2 = fmaxf(aA1[2],0.f), c3 = fmaxf(aA1[3],0.f);
        unsigned u0,u1,u2,u3;
        asm("v_cvt_pk_bf16_f32 %0, %1, %2" : "=v"(u0) : "v"(a0), "v"(a1));
        asm("v_cvt_pk_bf16_f32 %0, %1, %2" : "=v"(u1) : "v"(a2), "v"(a3));
        asm("v_cvt_pk_bf16_f32 %0, %1, %2" : "=v"(u2) : "v"(c0), "v"(c1));
        asm("v_cvt_pk_bf16_f32 %0, %1, %2" : "=v"(u3) : "v"(c2), "v"(c3));
        U16x8 uu; uu.u.x = u0; uu.u.y = u1; uu.u.z = u2; uu.u.w = u3;
        eA = __builtin_amdgcn_mfma_f32_16x16x32_bf16(uu.s, w1u[p].s, eA, 0, 0, 0);
      }
      {
        float a0 = fmaxf(aB0[0],0.f), a1 = fmaxf(aB0[1],0.f), a2 = fmaxf(aB0[2],0.f), a3 = fmaxf(aB0[3],0.f);
        float c0 = fmaxf(aB1[0],0.f), c1 = fmaxf(aB1[1],0.f), c2 = fmaxf(aB1[2],0.f), c3 = fmaxf(aB1[3],0.f);
        unsigned u0,u1,u2,u3;
        asm("v_cvt_pk_bf16_f32 %0, %1, %2" : "=v"(u0) : "v"(a0), "v"(a1));
        asm("v_cvt_pk_bf16_f32 %0, %1, %2" : "=v"(u1) : "v"(a2), "v"(a3));
        asm("v_cvt_pk_bf16_f32 %0, %1, %2" : "=v"(u2) : "v"(c0), "v"(c1));
        asm("v_cvt_pk_bf16_f32 %0, %1, %2" : "=v"(u3) : "v"(c2), "v"(c3));
        U16x8 uu; uu.u.x = u0; uu.u.y = u1; uu.u.z = u2; uu.u.w = u3;
        eB = __builtin_amdgcn_mfma_f32_16x16x32_bf16(uu.s, w1u[p].s, eB, 0, 0, 0);
      }
    }

    if (lr == 0) {
      *(float4*)(outp + el0 * MM) = *(float4*)&eA;
      *(float4*)(outp + el1 * MM) = *(float4*)&eB;
    }
  }
}

extern "C" void kernel_launch(void* const* d_in, const int* in_sizes, int n_in,
                              void* d_out, int out_size, void* d_ws, size_t ws_size,
                              hipStream_t stream) {
  const float* X   = (const float*)d_in[0];
  const float* inc = (const float*)d_in[1];
  const float* Wkk = (const float*)d_in[2];
  const float* bkk = (const float*)d_in[3];
  const float* w1  = (const float*)d_in[4];
  const float* b1  = (const float*)d_in[5];
  float* out = (float*)d_out;

  unsigned short* P1g = (unsigned short*)d_ws;          // 32*128*128 u16 = 1 MB
  unsigned short* XTg = P1g + NN * MM * DD;             // 1 MB
  unsigned short* P0g = XTg + NN * MM * DD;             // 32 KB
  unsigned* bmap = (unsigned*)(P0g + MM * MM);          // 32*256*4 u32 = 128 KB

  hipLaunchKernelGGL(k_prep, dim3(128), dim3(128), 0, stream, X, Wkk, bkk, P1g, P0g);
  hipLaunchKernelGGL(k_aux,  dim3(32),  dim3(256), 0, stream, X, inc, XTg, bmap);
  hipLaunchKernelGGL(k_main, dim3(1024), dim3(256), 0, stream, P0g, P1g, XTg, bmap, w1, b1, out);
}

// Round 10
// 52.445 us; speedup vs baseline: 1.5621x; 1.1078x over previous
//
#include <hip/hip_runtime.h>

#define NN 32
#define MM 128
#define EE 256
#define DD 128
#define ELB 32   // e's per k_main block

typedef __attribute__((ext_vector_type(8))) short short8;
typedef __attribute__((ext_vector_type(4))) float f32x4;

union U16x8 { uint4 u; short8 s; };

static __device__ __forceinline__ unsigned short f2bf(float f) {
  union { float f; unsigned u; } v; v.f = f;
  unsigned r = v.u + 0x7FFFu + ((v.u >> 16) & 1u);   // RNE
  return (unsigned short)(r >> 16);
}

// ---------------- kernel 1 (merged): blocks 0..127 = prep(i); 128..191 = xt half-tiles; 192..319 = binc ----
__global__ __launch_bounds__(256, 1)
void k_pre(const float* __restrict__ X, const float* __restrict__ inc,
           const float* __restrict__ Wkk, const float* __restrict__ bkk,
           unsigned short* __restrict__ P1g, unsigned short* __restrict__ P0g,
           unsigned short* __restrict__ XTg, unsigned* __restrict__ bmap) {
  __shared__ float xs[64][129];
  const int bid = blockIdx.x;
  const int t = threadIdx.x;

  if (bid < 128) {  // ---- prep: L = X[n,i,:]·Wkk[i,j,:], softmax -> P1; P0 = softmax(bkk) ----
    if (t >= 128) return;
    const int i  = bid;
    const int ty = t >> 6;
    const int l  = t & 63;
    const int lr = l & 15, lg = l >> 4;

    short8 a[4];
    {
      const int n = ty * 16 + lr;
      const float* xp = X + (n * MM + i) * DD + lg * 8;
#pragma unroll
      for (int k = 0; k < 4; ++k) {
        float4 v0 = *(const float4*)(xp + k * 32);
        float4 v1 = *(const float4*)(xp + k * 32 + 4);
        short8 s;
        s[0]=(short)f2bf(v0.x); s[1]=(short)f2bf(v0.y); s[2]=(short)f2bf(v0.z); s[3]=(short)f2bf(v0.w);
        s[4]=(short)f2bf(v1.x); s[5]=(short)f2bf(v1.y); s[6]=(short)f2bf(v1.z); s[7]=(short)f2bf(v1.w);
        a[k] = s;
      }
    }
    f32x4 acc[8];
#pragma unroll
    for (int cf = 0; cf < 8; ++cf) acc[cf] = (f32x4){0.f, 0.f, 0.f, 0.f};
#pragma unroll
    for (int k = 0; k < 4; ++k) {
#pragma unroll
      for (int cf = 0; cf < 8; ++cf) {
        const int j = cf * 16 + lr;
        const float* wp = Wkk + (i * MM + j) * DD + k * 32 + lg * 8;
        float4 v0 = *(const float4*)(wp);
        float4 v1 = *(const float4*)(wp + 4);
        short8 b;
        b[0]=(short)f2bf(v0.x); b[1]=(short)f2bf(v0.y); b[2]=(short)f2bf(v0.z); b[3]=(short)f2bf(v0.w);
        b[4]=(short)f2bf(v1.x); b[5]=(short)f2bf(v1.y); b[6]=(short)f2bf(v1.z); b[7]=(short)f2bf(v1.w);
        acc[cf] = __builtin_amdgcn_mfma_f32_16x16x32_bf16(a[k], b, acc[cf], 0, 0, 0);
      }
    }
    float bk[8];
#pragma unroll
    for (int cf = 0; cf < 8; ++cf) bk[cf] = bkk[i * MM + cf * 16 + lr];
#pragma unroll
    for (int r = 0; r < 4; ++r) {
      float v[8], m = -1e30f;
#pragma unroll
      for (int cf = 0; cf < 8; ++cf) { v[cf] = acc[cf][r] + bk[cf]; m = fmaxf(m, v[cf]); }
#pragma unroll
      for (int s = 1; s < 16; s <<= 1) m = fmaxf(m, __shfl_xor(m, s, 64));
      float sum = 0.f;
#pragma unroll
      for (int cf = 0; cf < 8; ++cf) { v[cf] = __expf(v[cf] - m); sum += v[cf]; }
#pragma unroll
      for (int s = 1; s < 16; s <<= 1) sum += __shfl_xor(sum, s, 64);
      const float inv = 1.f / sum;
      const int n = ty * 16 + lg * 4 + r;
      unsigned short* dst = P1g + (n * MM + i) * MM;
#pragma unroll
      for (int cf = 0; cf < 8; ++cf) dst[cf * 16 + lr] = f2bf(v[cf] * inv);
    }
    if (ty == 0) {  // P0 row i
      float v0 = bkk[i * MM + l], v1 = bkk[i * MM + 64 + l];
      float m = fmaxf(v0, v1);
#pragma unroll
      for (int s = 1; s < 64; s <<= 1) m = fmaxf(m, __shfl_xor(m, s, 64));
      v0 = __expf(v0 - m); v1 = __expf(v1 - m);
      float sum = v0 + v1;
#pragma unroll
      for (int s = 1; s < 64; s <<= 1) sum += __shfl_xor(sum, s, 64);
      const float inv = 1.f / sum;
      P0g[i * MM + l]      = f2bf(v0 * inv);
      P0g[i * MM + 64 + l] = f2bf(v1 * inv);
    }
  } else if (bid < 192) {  // ---- xt: XT[n][d][j] = bf16(X[n][j][d]), half-tile (64 j's) ----
    const int idx = bid - 128;
    const int n = idx >> 1, jh = idx & 1;
#pragma unroll
    for (int it = 0; it < 8; ++it) {
      int id2 = it * 256 + t;           // 0..2047 float4 tiles of the 64x128 half
      int j = id2 >> 5, dq = id2 & 31;
      float4 v = *(const float4*)(X + (n * MM + jh * 64 + j) * DD + dq * 4);
      xs[j][dq * 4 + 0] = v.x; xs[j][dq * 4 + 1] = v.y;
      xs[j][dq * 4 + 2] = v.z; xs[j][dq * 4 + 3] = v.w;
    }
    __syncthreads();
    const int d = t >> 1, half = t & 1;
    unsigned* dst = (unsigned*)XTg + (n * DD + d) * (MM / 2) + jh * 32 + half * 16;
#pragma unroll
    for (int wq = 0; wq < 16; ++wq) {
      int jl = half * 32 + wq * 2;
      unsigned u0 = f2bf(xs[jl][d]), u1 = f2bf(xs[jl + 1][d]);
      dst[wq] = u0 | (u1 << 16);
    }
  } else {  // ---- binc: bitmap word q for 32 j's, e = t ----
    const int idx = bid - 192;
    const int n = idx >> 2, q = idx & 3;
    const int e = t;
    unsigned bm = 0;
#pragma unroll 4
    for (int j = 0; j < 32; ++j)
      if (inc[(n * MM + q * 32 + j) * EE + e] != 0.f) bm |= 1u << j;
    bmap[(n * EE + e) * 4 + q] = bm;
  }
}

// ---------------- kernel 2: main. 512 blocks = 32n x 8eg x 2rh. T^T = XT * P^T, X pinned in regs. ----
__global__ __launch_bounds__(256, 2)
void k_main(const unsigned short* __restrict__ P0g, const unsigned short* __restrict__ P1g,
            const unsigned short* __restrict__ XTg, const unsigned* __restrict__ bmap,
            const float* __restrict__ w1, const float* __restrict__ b1p,
            float* __restrict__ out) {
  __shared__ unsigned bitm[ELB][4];
  __shared__ alignas(16) unsigned short mrow[ELB][128];     // 8 KB

  const int bid = blockIdx.x;
  const int n = bid & 31, eg = (bid >> 5) & 7, rh = bid >> 8;
  const int t = threadIdx.x, w = t >> 6, l = t & 63, lr = l & 15, lg = l >> 4;
  const int i_lane = rh * 64 + w * 16 + lr;   // this lane's P row / output-col index

  if (t < ELB)
    *(uint4*)&bitm[t][0] = *(const uint4*)(bmap + (n * EE + eg * ELB + t) * 4);

  // X fragments (A-operands, el-invariant): rows d = cf*16+lr -- loaded ONCE from global, pinned
  uint4 x[8][4];
  {
    const unsigned short* xb = XTg + n * DD * MM;
#pragma unroll
    for (int cf = 0; cf < 8; ++cf)
#pragma unroll
      for (int k = 0; k < 4; ++k)
        x[cf][k] = *(const uint4*)(xb + (cf * 16 + lr) * MM + k * 32 + lg * 8);
  }
  // P fragments (B-operands): row i_lane, k-slices -- loaded ONCE, pinned
  uint4 p0[4], p1[4];
  {
    const unsigned short* pb0 = P0g + i_lane * MM;
    const unsigned short* pb1 = P1g + n * MM * MM + i_lane * MM;
#pragma unroll
    for (int k = 0; k < 4; ++k) {
      p0[k] = *(const uint4*)(pb0 + k * 32 + lg * 8);
      p1[k] = *(const uint4*)(pb1 + k * 32 + lg * 8);
    }
  }
  // w1 B-fragments, packed per cf-pair for the K=32 epilogue contraction
  U16x8 w1u[4];
#pragma unroll
  for (int p = 0; p < 4; ++p) {
    float4 a = *(const float4*)(w1 + (2 * p) * 16 + lg * 4);
    float4 b = *(const float4*)(w1 + (2 * p + 1) * 16 + lg * 4);
    short8 s;
    s[0]=(short)f2bf(a.x); s[1]=(short)f2bf(a.y); s[2]=(short)f2bf(a.z); s[3]=(short)f2bf(a.w);
    s[4]=(short)f2bf(b.x); s[5]=(short)f2bf(b.y); s[6]=(short)f2bf(b.z); s[7]=(short)f2bf(b.w);
    w1u[p].s = s;
  }
  // PIN all loop-invariants: read-write asm forbids sinking/remat of the loads.
#pragma unroll
  for (int cf = 0; cf < 8; ++cf) {
#pragma unroll
    for (int k = 0; k < 4; ++k)
      asm volatile("" : "+v"(x[cf][k].x), "+v"(x[cf][k].y), "+v"(x[cf][k].z), "+v"(x[cf][k].w));
  }
#pragma unroll
  for (int k = 0; k < 4; ++k) {
    asm volatile("" : "+v"(p0[k].x), "+v"(p0[k].y), "+v"(p0[k].z), "+v"(p0[k].w));
    asm volatile("" : "+v"(p1[k].x), "+v"(p1[k].y), "+v"(p1[k].z), "+v"(p1[k].w));
    asm volatile("" : "+v"(w1u[k].u.x), "+v"(w1u[k].u.y), "+v"(w1u[k].u.z), "+v"(w1u[k].u.w));
  }
  const float b1v = b1p[0];
  const int selsh = (w & 1) * 16 + lr;
  const int selwd = rh * 2 + (w >> 1);
  __syncthreads();

  {  // expand bitmap -> u16 AND-masks over contracted dim j (all 256 threads)
    int el = t >> 3, j0 = (t & 7) * 16;
    unsigned wd = bitm[el][j0 >> 5];
    int sh = j0 & 31;
    unsigned short* mp = &mrow[el][j0];
#pragma unroll
    for (int b = 0; b < 16; ++b) mp[b] = ((wd >> (sh + b)) & 1u) ? 0xFFFFu : 0u;
  }
  __syncthreads();

  float* outp = out + (n * EE + eg * ELB) * MM + rh * 64 + w * 16 + lg * 4;

#pragma unroll 1
  for (int el = 0; el < ELB; ++el) {
    const bool sel = ((bitm[el][selwd] >> selsh) & 1u) != 0u;

    // select+mask P once per e (k-slices)
    U16x8 pv[4];
#pragma unroll
    for (int k = 0; k < 4; ++k) {
      uint4 mm = *(const uint4*)((const char*)&mrow[el][0] + k * 64 + lg * 16);
      pv[k].u.x = (sel ? p1[k].x : p0[k].x) & mm.x;
      pv[k].u.y = (sel ? p1[k].y : p0[k].y) & mm.y;
      pv[k].u.z = (sel ? p1[k].z : p0[k].z) & mm.z;
      pv[k].u.w = (sel ? p1[k].w : p0[k].w) & mm.w;
    }

    f32x4 eA = (f32x4){b1v, b1v, b1v, b1v};
#pragma unroll
    for (int p = 0; p < 4; ++p) {
      f32x4 a0v = (f32x4){0.f,0.f,0.f,0.f}, a1v = (f32x4){0.f,0.f,0.f,0.f};
#pragma unroll
      for (int k = 0; k < 4; ++k) {
        U16x8 xv0; xv0.u = x[2*p][k];
        U16x8 xv1; xv1.u = x[2*p+1][k];
        a0v = __builtin_amdgcn_mfma_f32_16x16x32_bf16(xv0.s, pv[k].s, a0v, 0, 0, 0);
        a1v = __builtin_amdgcn_mfma_f32_16x16x32_bf16(xv1.s, pv[k].s, a1v, 0, 0, 0);
      }
      float f0 = fmaxf(a0v[0],0.f), f1 = fmaxf(a0v[1],0.f), f2 = fmaxf(a0v[2],0.f), f3 = fmaxf(a0v[3],0.f);
      float g0 = fmaxf(a1v[0],0.f), g1 = fmaxf(a1v[1],0.f), g2 = fmaxf(a1v[2],0.f), g3 = fmaxf(a1v[3],0.f);
      unsigned u0,u1,u2,u3;
      asm("v_cvt_pk_bf16_f32 %0, %1, %2" : "=v"(u0) : "v"(f0), "v"(f1));
      asm("v_cvt_pk_bf16_f32 %0, %1, %2" : "=v"(u1) : "v"(f2), "v"(f3));
      asm("v_cvt_pk_bf16_f32 %0, %1, %2" : "=v"(u2) : "v"(g0), "v"(g1));
      asm("v_cvt_pk_bf16_f32 %0, %1, %2" : "=v"(u3) : "v"(g2), "v"(g3));
      U16x8 uu; uu.u.x = u0; uu.u.y = u1; uu.u.z = u2; uu.u.w = u3;
      eA = __builtin_amdgcn_mfma_f32_16x16x32_bf16(uu.s, w1u[p].s, eA, 0, 0, 0);
    }

    if (lr == 0) *(float4*)(outp + el * MM) = *(float4*)&eA;
  }
}

extern "C" void kernel_launch(void* const* d_in, const int* in_sizes, int n_in,
                              void* d_out, int out_size, void* d_ws, size_t ws_size,
                              hipStream_t stream) {
  const float* X   = (const float*)d_in[0];
  const float* inc = (const float*)d_in[1];
  const float* Wkk = (const float*)d_in[2];
  const float* bkk = (const float*)d_in[3];
  const float* w1  = (const float*)d_in[4];
  const float* b1  = (const float*)d_in[5];
  float* out = (float*)d_out;

  unsigned short* P1g = (unsigned short*)d_ws;          // 32*128*128 u16 = 1 MB
  unsigned short* XTg = P1g + NN * MM * DD;             // 1 MB
  unsigned short* P0g = XTg + NN * MM * DD;             // 32 KB
  unsigned* bmap = (unsigned*)(P0g + MM * MM);          // 32*256*4 u32 = 128 KB

  hipLaunchKernelGGL(k_pre,  dim3(320), dim3(256), 0, stream, X, inc, Wkk, bkk, P1g, P0g, XTg, bmap);
  hipLaunchKernelGGL(k_main, dim3(512), dim3(256), 0, stream, P0g, P1g, XTg, bmap, w1, b1, out);
}